// Round 21
// baseline (82.122 us; speedup 1.0000x reference)
//
#include <hip/hip_runtime.h>
#include <hip/hip_fp16.h>

// GCNConv (self-loops, symmetric norm) + bias + PReLU, fp32, N=100k, D=64, E=1.6M.
//
// Padded-bucket front end; MFMA-f16 gemm with fused meta; half-bucket gather
// with 8-lane row groups (16B/lane -> 8 rows per wave load instruction):
//   0. memset:     gcur[nbuk] = 0 (bucket fill counters)
//   1. k_scat:     per-wave inline layout-detect; single-read register-buffered
//                  pass; LDS count -> one global atomicAdd per (block,bucket)
//                  -> LDS-rank write of (dst&127)<<17|src into padded part[]
//   2. k_gemmmeta: block bb = bucket bb = row tile bb (128 rows). Counts its
//                  part segment + scan -> meta[d]=(cnt,exc), dinv in LDS; then
//                  xwsh = fp16((x @ W) * dinv[row]) via mfma_f32_16x16x32_f16.
//   3. k_gfuse:    TWO blocks per bucket (64 dsts each): rank-place this
//                  half's csr in LDS using meta, then 8-deep unrolled gather,
//                  8 lanes per row (uint4); fused self-loop+bias+PReLU.

static inline int iceil(long long a, int b) { return (int)((a + (long long)b - 1) / b); }

#define CAP 4096          // padded slots per 128-dst bucket (mean fill ~2046)
#define NBUK_MAX 1024     // supports N <= 131072
#define SCTH 1024         // scatter block threads
#define BUFK 8            // edges buffered per thread (chunk <= SCTH*BUFK)

typedef __attribute__((ext_vector_type(8))) _Float16 half8;
typedef __attribute__((ext_vector_type(4))) float floatx4;

// single-READ scatter with inline layout detect: buffer <=BUFK edges in
// registers, LDS count, one global reserve atomic per nonempty (block,bucket),
// LDS-rank place from registers.
__global__ __launch_bounds__(SCTH) void k_scat(const int* __restrict__ ei,
                                               int* __restrict__ gcur,
                                               int* __restrict__ part,
                                               long long E, int nbuk, int chunk,
                                               long long n_i32) {
    __shared__ int hist[NBUK_MAX];
    __shared__ int sbase[NBUK_MAX];
    const int t = threadIdx.x;
    // per-wave layout detect: sample 64 odd int32 slots spread over the array.
    // int64 (values < 2^31) -> all high words zero -> stride st=2; else st=1.
    long long half = n_i32 >> 1;
    long long step = half >> 6;
    if (step == 0) step = 1;
    long long sk = (long long)(t & 63) * step;
    int sample = (sk < half) ? ei[2 * sk + 1] : 0;
    const int st = __any(sample != 0) ? 1 : 2;

    for (int i = t; i < nbuk; i += SCTH) hist[i] = 0;
    __syncthreads();
    const long long beg = (long long)blockIdx.x * chunk;
    long long end = beg + chunk; if (end > E) end = E;

    int bs[BUFK], bd[BUFK];
#pragma unroll
    for (int kk = 0; kk < BUFK; ++kk) {
        long long e = beg + t + (long long)kk * SCTH;
        bool v = e < end;
        bs[kk] = v ? ei[e * st] : 0;
        bd[kk] = v ? ei[(E + e) * st] : -1;
    }
#pragma unroll
    for (int kk = 0; kk < BUFK; ++kk)
        if (bd[kk] >= 0) atomicAdd(&hist[bd[kk] >> 7], 1);
    __syncthreads();
    for (int i = t; i < nbuk; i += SCTH) {
        int c = hist[i];
        sbase[i] = c ? (i * CAP + atomicAdd(&gcur[i], c)) : 0;
        hist[i] = 0;  // reuse as rank counter
    }
    __syncthreads();
#pragma unroll
    for (int kk = 0; kk < BUFK; ++kk) {
        if (bd[kk] >= 0) {
            int b = bd[kk] >> 7;
            int r = atomicAdd(&hist[b], 1);
            part[sbase[b] + r] = ((bd[kk] & 127) << 17) | bs[kk];  // s < 2^17
        }
    }
}

// fused meta + MFMA gemm: block bb = bucket bb = row tile bb (128 rows).
// Phase A: count part segment per dst + scan -> meta (for gfuse), dinv in LDS.
// Phase B: xwsh = fp16((x @ W) * dinvL[row]) via v_mfma_f32_16x16x32_f16.
__global__ __launch_bounds__(256) void k_gemmmeta(const int* __restrict__ part,
                                                  const int* __restrict__ gcur,
                                                  const float* __restrict__ x,
                                                  const float* __restrict__ W,
                                                  int2* __restrict__ meta,
                                                  __half* __restrict__ xwsh, int N) {
    __shared__ _Float16 Wth[64 * 64];   // [n][k] transposed, 8 KB
    __shared__ int cnt[128], inc[128];
    __shared__ float dinvL[128];
    const int tid = threadIdx.x;
    const int bb = blockIdx.x;
    const int tile0 = bb * 128;

    if (tid < 128) cnt[tid] = 0;
    __syncthreads();

    // stage W transposed as f16 (one-time, 4096 elems)
    {
        const float4* W4 = (const float4*)W;
#pragma unroll
        for (int j = 0; j < 4; ++j) {
            int idx = tid + 256 * j;        // float4 index into 64x64
            float4 v = W4[idx];
            int k = idx >> 4;               // row of W (k dim)
            int n0 = (idx & 15) * 4;        // col base
            Wth[(n0 + 0) * 64 + k] = (_Float16)v.x;
            Wth[(n0 + 1) * 64 + k] = (_Float16)v.y;
            Wth[(n0 + 2) * 64 + k] = (_Float16)v.z;
            Wth[(n0 + 3) * 64 + k] = (_Float16)v.w;
        }
    }
    // count this bucket's part segment
    {
        const int beg = bb * CAP, end = bb * CAP + gcur[bb];
        for (int i = beg + tid; i < end; i += 256)
            atomicAdd(&cnt[(part[i] >> 17) & 127], 1);
    }
    __syncthreads();
    if (tid < 128) inc[tid] = cnt[tid];
    __syncthreads();
    for (int off = 1; off < 128; off <<= 1) {
        int v = (tid < 128 && tid >= off) ? inc[tid - off] : 0;
        __syncthreads();
        if (tid < 128) inc[tid] += v;
        __syncthreads();
    }
    if (tid < 128) {
        dinvL[tid] = rsqrtf((float)cnt[tid] + 1.0f);  // +1 self loop
        int d = tile0 + tid;
        if (d < N) meta[d] = make_int2(cnt[tid], inc[tid] - cnt[tid]);
    }
    __syncthreads();

    const int lane = tid & 63;
    const int w = tid >> 6;          // wave 0..3
    const int mrow = lane & 15;
    const int kq = lane >> 4;        // 0..3

    // B fragments: 4 col-tiles x 2 K-steps, each one 16B LDS read
    half8 bf[4][2];
#pragma unroll
    for (int ct = 0; ct < 4; ++ct)
#pragma unroll
        for (int ks = 0; ks < 2; ++ks)
            bf[ct][ks] = *(const half8*)&Wth[(ct * 16 + mrow) * 64 + ks * 32 + kq * 8];

#pragma unroll
    for (int p = 0; p < 2; ++p) {
        const int rt = w * 2 + p;               // row tile 0..7
        int gr = tile0 + rt * 16 + mrow;
        if (gr >= N) gr = N - 1;                // clamp (stores guarded)
        const float* xr = x + (long long)gr * 64 + kq * 8;
        float4 u0 = *(const float4*)xr;
        float4 u1 = *(const float4*)(xr + 4);
        float4 u2 = *(const float4*)(xr + 32);
        float4 u3 = *(const float4*)(xr + 36);
        half8 a0, a1;
        a0[0] = (_Float16)u0.x; a0[1] = (_Float16)u0.y;
        a0[2] = (_Float16)u0.z; a0[3] = (_Float16)u0.w;
        a0[4] = (_Float16)u1.x; a0[5] = (_Float16)u1.y;
        a0[6] = (_Float16)u1.z; a0[7] = (_Float16)u1.w;
        a1[0] = (_Float16)u2.x; a1[1] = (_Float16)u2.y;
        a1[2] = (_Float16)u2.z; a1[3] = (_Float16)u2.w;
        a1[4] = (_Float16)u3.x; a1[5] = (_Float16)u3.y;
        a1[6] = (_Float16)u3.z; a1[7] = (_Float16)u3.w;
#pragma unroll
        for (int ct = 0; ct < 4; ++ct) {
            floatx4 acc = {0.f, 0.f, 0.f, 0.f};
            acc = __builtin_amdgcn_mfma_f32_16x16x32_f16(a0, bf[ct][0], acc, 0, 0, 0);
            acc = __builtin_amdgcn_mfma_f32_16x16x32_f16(a1, bf[ct][1], acc, 0, 0, 0);
#pragma unroll
            for (int r = 0; r < 4; ++r) {
                int m = rt * 16 + kq * 4 + r;   // C/D row
                int d = tile0 + m;
                if (d < N)
                    xwsh[(long long)d * 64 + ct * 16 + mrow] =
                        __float2half(acc[r] * dinvL[m]);
            }
        }
    }
}

// half-bucket gather, 8-lane row groups: block = (bucket bb, half h).
// Rank-place this half's 64 dsts into LDS csr, then gather: 8-lane group owns
// one dst at a time (8 features/lane via uint4), 8-deep unrolled row loads
// (one wave load instruction covers 8 rows = 1KB).
__global__ __launch_bounds__(256) void k_gfuse(const int* __restrict__ part,
                                               const int* __restrict__ gcur,
                                               const int2* __restrict__ meta,
                                               const __half* __restrict__ xwsh,
                                               const float* __restrict__ b,
                                               const float* __restrict__ pa,
                                               float* __restrict__ out, int N) {
    __shared__ int cnt[64], excL[64], rnk[64];
    __shared__ int lcsr[CAP / 2];
    const int t = threadIdx.x;
    const int bb = blockIdx.x >> 1;
    const int h = blockIdx.x & 1;
    const int tile0 = bb * 128;
    const int d0 = tile0 + h * 64;
    if (d0 >= N) return;
    const int beg = bb * CAP, end = bb * CAP + gcur[bb];
    const int excb = meta[d0].y;   // broadcast load (same addr all lanes)
    if (t < 64) {
        int d = d0 + t;
        int2 m = (d < N) ? meta[d] : make_int2(0, 0);
        cnt[t] = m.x;
        excL[t] = m.y - excb;      // invalid dsts: never referenced (cnt=0)
        rnk[t] = 0;
    }
    __syncthreads();
    for (int i = beg + t; i < end; i += 256) {
        int v = part[i];
        int dl = (v >> 17) & 127;
        if ((dl >> 6) == h) {
            int l = dl & 63;
            int r = atomicAdd(&rnk[l], 1);
            lcsr[excL[l] + r] = v & 0x1FFFF;
        }
    }
    __syncthreads();

    const int lane = t & 63;
    const int g = lane >> 3;        // group 0..7 within wave (8 lanes each)
    const int fe = lane & 7;        // feature octet: features 8*fe .. 8*fe+7
    const int wib = t >> 6;         // wave 0..3
    const int q = wib * 8 + g;      // group 0..31 in block
    const float slope = pa[0];
    const float4 bA = ((const float4*)b)[2 * fe];
    const float4 bB = ((const float4*)b)[2 * fe + 1];

#define CVT8(U, P0, P1, P2, P3)                                               \
    float2 P0 = __half22float2(*(const __half2*)&(U).x);                      \
    float2 P1 = __half22float2(*(const __half2*)&(U).y);                      \
    float2 P2 = __half22float2(*(const __half2*)&(U).z);                      \
    float2 P3 = __half22float2(*(const __half2*)&(U).w);

    for (int dl = q; dl < 64; dl += 32) {
        int d = d0 + dl;
        if (d >= N) break;
        const int jb = excL[dl];
        const int n = cnt[dl];
        float a0 = 0.f, a1 = 0.f, a2 = 0.f, a3 = 0.f;
        float a4 = 0.f, a5 = 0.f, a6 = 0.f, a7 = 0.f;
        int j = 0;
        for (; j + 7 < n; j += 8) {
            int s0 = lcsr[jb + j],     s1 = lcsr[jb + j + 1];
            int s2 = lcsr[jb + j + 2], s3 = lcsr[jb + j + 3];
            int s4 = lcsr[jb + j + 4], s5 = lcsr[jb + j + 5];
            int s6 = lcsr[jb + j + 6], s7 = lcsr[jb + j + 7];
            uint4 u0 = *(const uint4*)(xwsh + (long long)s0 * 64 + 8 * fe);
            uint4 u1 = *(const uint4*)(xwsh + (long long)s1 * 64 + 8 * fe);
            uint4 u2 = *(const uint4*)(xwsh + (long long)s2 * 64 + 8 * fe);
            uint4 u3 = *(const uint4*)(xwsh + (long long)s3 * 64 + 8 * fe);
            uint4 u4 = *(const uint4*)(xwsh + (long long)s4 * 64 + 8 * fe);
            uint4 u5 = *(const uint4*)(xwsh + (long long)s5 * 64 + 8 * fe);
            uint4 u6 = *(const uint4*)(xwsh + (long long)s6 * 64 + 8 * fe);
            uint4 u7 = *(const uint4*)(xwsh + (long long)s7 * 64 + 8 * fe);
            CVT8(u0, p00, p01, p02, p03)
            CVT8(u1, p10, p11, p12, p13)
            CVT8(u2, p20, p21, p22, p23)
            CVT8(u3, p30, p31, p32, p33)
            CVT8(u4, p40, p41, p42, p43)
            CVT8(u5, p50, p51, p52, p53)
            CVT8(u6, p60, p61, p62, p63)
            CVT8(u7, p70, p71, p72, p73)
            a0 += ((p00.x + p10.x) + (p20.x + p30.x)) +
                  ((p40.x + p50.x) + (p60.x + p70.x));
            a1 += ((p00.y + p10.y) + (p20.y + p30.y)) +
                  ((p40.y + p50.y) + (p60.y + p70.y));
            a2 += ((p01.x + p11.x) + (p21.x + p31.x)) +
                  ((p41.x + p51.x) + (p61.x + p71.x));
            a3 += ((p01.y + p11.y) + (p21.y + p31.y)) +
                  ((p41.y + p51.y) + (p61.y + p71.y));
            a4 += ((p02.x + p12.x) + (p22.x + p32.x)) +
                  ((p42.x + p52.x) + (p62.x + p72.x));
            a5 += ((p02.y + p12.y) + (p22.y + p32.y)) +
                  ((p42.y + p52.y) + (p62.y + p72.y));
            a6 += ((p03.x + p13.x) + (p23.x + p33.x)) +
                  ((p43.x + p53.x) + (p63.x + p73.x));
            a7 += ((p03.y + p13.y) + (p23.y + p33.y)) +
                  ((p43.y + p53.y) + (p63.y + p73.y));
        }
        for (; j + 3 < n; j += 4) {
            int s0 = lcsr[jb + j],     s1 = lcsr[jb + j + 1];
            int s2 = lcsr[jb + j + 2], s3 = lcsr[jb + j + 3];
            uint4 u0 = *(const uint4*)(xwsh + (long long)s0 * 64 + 8 * fe);
            uint4 u1 = *(const uint4*)(xwsh + (long long)s1 * 64 + 8 * fe);
            uint4 u2 = *(const uint4*)(xwsh + (long long)s2 * 64 + 8 * fe);
            uint4 u3 = *(const uint4*)(xwsh + (long long)s3 * 64 + 8 * fe);
            CVT8(u0, p00, p01, p02, p03)
            CVT8(u1, p10, p11, p12, p13)
            CVT8(u2, p20, p21, p22, p23)
            CVT8(u3, p30, p31, p32, p33)
            a0 += (p00.x + p10.x) + (p20.x + p30.x);
            a1 += (p00.y + p10.y) + (p20.y + p30.y);
            a2 += (p01.x + p11.x) + (p21.x + p31.x);
            a3 += (p01.y + p11.y) + (p21.y + p31.y);
            a4 += (p02.x + p12.x) + (p22.x + p32.x);
            a5 += (p02.y + p12.y) + (p22.y + p32.y);
            a6 += (p03.x + p13.x) + (p23.x + p33.x);
            a7 += (p03.y + p13.y) + (p23.y + p33.y);
        }
        for (; j < n; ++j) {
            int s = lcsr[jb + j];
            uint4 u = *(const uint4*)(xwsh + (long long)s * 64 + 8 * fe);
            CVT8(u, p0, p1, p2, p3)
            a0 += p0.x; a1 += p0.y; a2 += p1.x; a3 += p1.y;
            a4 += p2.x; a5 += p2.y; a6 += p3.x; a7 += p3.y;
        }
        uint4 u = *(const uint4*)(xwsh + (long long)d * 64 + 8 * fe);  // self
        CVT8(u, s0p, s1p, s2p, s3p)
        float di = rsqrtf((float)n + 1.0f);
        float4 vA, vB;
        vA.x = di * (a0 + s0p.x) + bA.x;
        vA.y = di * (a1 + s0p.y) + bA.y;
        vA.z = di * (a2 + s1p.x) + bA.z;
        vA.w = di * (a3 + s1p.y) + bA.w;
        vB.x = di * (a4 + s2p.x) + bB.x;
        vB.y = di * (a5 + s2p.y) + bB.y;
        vB.z = di * (a6 + s3p.x) + bB.z;
        vB.w = di * (a7 + s3p.y) + bB.w;
        vA.x = vA.x >= 0.f ? vA.x : slope * vA.x;
        vA.y = vA.y >= 0.f ? vA.y : slope * vA.y;
        vA.z = vA.z >= 0.f ? vA.z : slope * vA.z;
        vA.w = vA.w >= 0.f ? vA.w : slope * vA.w;
        vB.x = vB.x >= 0.f ? vB.x : slope * vB.x;
        vB.y = vB.y >= 0.f ? vB.y : slope * vB.y;
        vB.z = vB.z >= 0.f ? vB.z : slope * vB.z;
        vB.w = vB.w >= 0.f ? vB.w : slope * vB.w;
        *(float4*)(out + (long long)d * 64 + 8 * fe) = vA;
        *(float4*)(out + (long long)d * 64 + 8 * fe + 4) = vB;
    }
#undef CVT8
}

extern "C" void kernel_launch(void* const* d_in, const int* in_sizes, int n_in,
                              void* d_out, int out_size, void* d_ws, size_t ws_size,
                              hipStream_t stream) {
    const float* x  = (const float*)d_in[0];
    const int*   ei = (const int*)d_in[1];
    const float* W  = (const float*)d_in[2];
    const float* b  = (const float*)d_in[3];
    const float* pa = (const float*)d_in[4];
    float* out = (float*)d_out;

    const int N = in_sizes[0] / 64;
    const long long E = (long long)in_sizes[1] / 2;
    const int nbuk = (N + 127) >> 7;           // 782 for N=100k (<= NBUK_MAX)
    int nscat = iceil(E, SCTH * BUFK);
    if (nscat < 256) nscat = 256;              // keep all CUs busy
    const int chunk = iceil(E, nscat);

    char* ws = (char*)d_ws;
    size_t o = 0;
    int*    gcur  = (int*)(ws + o);   o += ((size_t)nbuk * 4 + 255) & ~(size_t)255;
    int2*   meta  = (int2*)(ws + o);  o += ((size_t)N * 8 + 255) & ~(size_t)255;
    int*    part  = (int*)(ws + o);   o += ((size_t)nbuk * CAP * 4 + 255) & ~(size_t)255;
    __half* xwsh  = (__half*)(ws + o);  // N*64*2 = 12.8 MB; total ~27 MB

    hipMemsetAsync(gcur, 0, (size_t)nbuk * 4, stream);
    k_scat<<<nscat, SCTH, 0, stream>>>(ei, gcur, part, E, nbuk, chunk,
                                       (long long)in_sizes[1]);
    k_gemmmeta<<<nbuk, 256, 0, stream>>>(part, gcur, x, W, meta, xwsh, N);
    k_gfuse<<<nbuk * 2, 256, 0, stream>>>(part, gcur, meta, xwsh, b, pa, out, N);
}

// Round 22
// 79.177 us; speedup vs baseline: 1.0372x; 1.0372x over previous
//
#include <hip/hip_runtime.h>
#include <hip/hip_fp16.h>

// GCNConv (self-loops, symmetric norm) + bias + PReLU, fp32, N=100k, D=64, E=1.6M.
//
// Padded-bucket front end; MFMA-f16 gemm with fused meta; half-bucket gather:
//   0. memset:     gcur[nbuk] = 0 (bucket fill counters)
//   1. k_scat:     per-wave inline layout-detect; single-read register-buffered
//                  pass; LDS count -> one global atomicAdd per (block,bucket)
//                  -> LDS-rank write of (dst&127)<<17|src into padded part[]
//   2. k_gemmmeta: block bb = bucket bb = row tile bb (128 rows). Counts its
//                  part segment + scan -> meta[d]=(cnt,exc), dinv in LDS; then
//                  xwsh = fp16((x @ W) * dinv[row]) via mfma_f32_16x16x32_f16.
//   3. k_gfuse:    TWO blocks per bucket (64 dsts each): rank-place this
//                  half's csr in LDS using meta, then 8-deep unrolled gather
//                  (16-lane groups, uint2 = 8B/lane); fused epilogue.
//
// R21 lesson: 8-lane/uint4 groups regress (occupancy 66->38%, lcsr bank
// conflicts 401k); 16-lane/uint2 is the measured optimum for the random-row
// gather, which sits at the L2-miss service floor (~2.4 TB/s effective).

static inline int iceil(long long a, int b) { return (int)((a + (long long)b - 1) / b); }

#define CAP 4096          // padded slots per 128-dst bucket (mean fill ~2046)
#define NBUK_MAX 1024     // supports N <= 131072
#define SCTH 1024         // scatter block threads
#define BUFK 8            // edges buffered per thread (chunk <= SCTH*BUFK)

typedef __attribute__((ext_vector_type(8))) _Float16 half8;
typedef __attribute__((ext_vector_type(4))) float floatx4;

// single-READ scatter with inline layout detect: buffer <=BUFK edges in
// registers, LDS count, one global reserve atomic per nonempty (block,bucket),
// LDS-rank place from registers.
__global__ __launch_bounds__(SCTH) void k_scat(const int* __restrict__ ei,
                                               int* __restrict__ gcur,
                                               int* __restrict__ part,
                                               long long E, int nbuk, int chunk,
                                               long long n_i32) {
    __shared__ int hist[NBUK_MAX];
    __shared__ int sbase[NBUK_MAX];
    const int t = threadIdx.x;
    // per-wave layout detect: sample 64 odd int32 slots spread over the array.
    // int64 (values < 2^31) -> all high words zero -> stride st=2; else st=1.
    long long half = n_i32 >> 1;
    long long step = half >> 6;
    if (step == 0) step = 1;
    long long sk = (long long)(t & 63) * step;
    int sample = (sk < half) ? ei[2 * sk + 1] : 0;
    const int st = __any(sample != 0) ? 1 : 2;

    for (int i = t; i < nbuk; i += SCTH) hist[i] = 0;
    __syncthreads();
    const long long beg = (long long)blockIdx.x * chunk;
    long long end = beg + chunk; if (end > E) end = E;

    int bs[BUFK], bd[BUFK];
#pragma unroll
    for (int kk = 0; kk < BUFK; ++kk) {
        long long e = beg + t + (long long)kk * SCTH;
        bool v = e < end;
        bs[kk] = v ? ei[e * st] : 0;
        bd[kk] = v ? ei[(E + e) * st] : -1;
    }
#pragma unroll
    for (int kk = 0; kk < BUFK; ++kk)
        if (bd[kk] >= 0) atomicAdd(&hist[bd[kk] >> 7], 1);
    __syncthreads();
    for (int i = t; i < nbuk; i += SCTH) {
        int c = hist[i];
        sbase[i] = c ? (i * CAP + atomicAdd(&gcur[i], c)) : 0;
        hist[i] = 0;  // reuse as rank counter
    }
    __syncthreads();
#pragma unroll
    for (int kk = 0; kk < BUFK; ++kk) {
        if (bd[kk] >= 0) {
            int b = bd[kk] >> 7;
            int r = atomicAdd(&hist[b], 1);
            part[sbase[b] + r] = ((bd[kk] & 127) << 17) | bs[kk];  // s < 2^17
        }
    }
}

// fused meta + MFMA gemm: block bb = bucket bb = row tile bb (128 rows).
// Phase A: count part segment per dst + scan -> meta (for gfuse), dinv in LDS.
// Phase B: xwsh = fp16((x @ W) * dinvL[row]) via v_mfma_f32_16x16x32_f16.
__global__ __launch_bounds__(256) void k_gemmmeta(const int* __restrict__ part,
                                                  const int* __restrict__ gcur,
                                                  const float* __restrict__ x,
                                                  const float* __restrict__ W,
                                                  int2* __restrict__ meta,
                                                  __half* __restrict__ xwsh, int N) {
    __shared__ _Float16 Wth[64 * 64];   // [n][k] transposed, 8 KB
    __shared__ int cnt[128], inc[128];
    __shared__ float dinvL[128];
    const int tid = threadIdx.x;
    const int bb = blockIdx.x;
    const int tile0 = bb * 128;

    if (tid < 128) cnt[tid] = 0;
    __syncthreads();

    // stage W transposed as f16 (one-time, 4096 elems)
    {
        const float4* W4 = (const float4*)W;
#pragma unroll
        for (int j = 0; j < 4; ++j) {
            int idx = tid + 256 * j;        // float4 index into 64x64
            float4 v = W4[idx];
            int k = idx >> 4;               // row of W (k dim)
            int n0 = (idx & 15) * 4;        // col base
            Wth[(n0 + 0) * 64 + k] = (_Float16)v.x;
            Wth[(n0 + 1) * 64 + k] = (_Float16)v.y;
            Wth[(n0 + 2) * 64 + k] = (_Float16)v.z;
            Wth[(n0 + 3) * 64 + k] = (_Float16)v.w;
        }
    }
    // count this bucket's part segment
    {
        const int beg = bb * CAP, end = bb * CAP + gcur[bb];
        for (int i = beg + tid; i < end; i += 256)
            atomicAdd(&cnt[(part[i] >> 17) & 127], 1);
    }
    __syncthreads();
    if (tid < 128) inc[tid] = cnt[tid];
    __syncthreads();
    for (int off = 1; off < 128; off <<= 1) {
        int v = (tid < 128 && tid >= off) ? inc[tid - off] : 0;
        __syncthreads();
        if (tid < 128) inc[tid] += v;
        __syncthreads();
    }
    if (tid < 128) {
        dinvL[tid] = rsqrtf((float)cnt[tid] + 1.0f);  // +1 self loop
        int d = tile0 + tid;
        if (d < N) meta[d] = make_int2(cnt[tid], inc[tid] - cnt[tid]);
    }
    __syncthreads();

    const int lane = tid & 63;
    const int w = tid >> 6;          // wave 0..3
    const int mrow = lane & 15;
    const int kq = lane >> 4;        // 0..3

    // B fragments: 4 col-tiles x 2 K-steps, each one 16B LDS read
    half8 bf[4][2];
#pragma unroll
    for (int ct = 0; ct < 4; ++ct)
#pragma unroll
        for (int ks = 0; ks < 2; ++ks)
            bf[ct][ks] = *(const half8*)&Wth[(ct * 16 + mrow) * 64 + ks * 32 + kq * 8];

#pragma unroll
    for (int p = 0; p < 2; ++p) {
        const int rt = w * 2 + p;               // row tile 0..7
        int gr = tile0 + rt * 16 + mrow;
        if (gr >= N) gr = N - 1;                // clamp (stores guarded)
        const float* xr = x + (long long)gr * 64 + kq * 8;
        float4 u0 = *(const float4*)xr;
        float4 u1 = *(const float4*)(xr + 4);
        float4 u2 = *(const float4*)(xr + 32);
        float4 u3 = *(const float4*)(xr + 36);
        half8 a0, a1;
        a0[0] = (_Float16)u0.x; a0[1] = (_Float16)u0.y;
        a0[2] = (_Float16)u0.z; a0[3] = (_Float16)u0.w;
        a0[4] = (_Float16)u1.x; a0[5] = (_Float16)u1.y;
        a0[6] = (_Float16)u1.z; a0[7] = (_Float16)u1.w;
        a1[0] = (_Float16)u2.x; a1[1] = (_Float16)u2.y;
        a1[2] = (_Float16)u2.z; a1[3] = (_Float16)u2.w;
        a1[4] = (_Float16)u3.x; a1[5] = (_Float16)u3.y;
        a1[6] = (_Float16)u3.z; a1[7] = (_Float16)u3.w;
#pragma unroll
        for (int ct = 0; ct < 4; ++ct) {
            floatx4 acc = {0.f, 0.f, 0.f, 0.f};
            acc = __builtin_amdgcn_mfma_f32_16x16x32_f16(a0, bf[ct][0], acc, 0, 0, 0);
            acc = __builtin_amdgcn_mfma_f32_16x16x32_f16(a1, bf[ct][1], acc, 0, 0, 0);
#pragma unroll
            for (int r = 0; r < 4; ++r) {
                int m = rt * 16 + kq * 4 + r;   // C/D row
                int d = tile0 + m;
                if (d < N)
                    xwsh[(long long)d * 64 + ct * 16 + mrow] =
                        __float2half(acc[r] * dinvL[m]);
            }
        }
    }
}

// half-bucket gather: block = (bucket bb, half h). Rank-place this half's 64
// dsts into LDS csr (offsets from meta, rebased), then gather: 16-lane group
// owns one dst at a time (4 features/lane), 8-deep unrolled row loads.
__global__ __launch_bounds__(256) void k_gfuse(const int* __restrict__ part,
                                               const int* __restrict__ gcur,
                                               const int2* __restrict__ meta,
                                               const __half* __restrict__ xwsh,
                                               const float* __restrict__ b,
                                               const float* __restrict__ pa,
                                               float* __restrict__ out, int N) {
    __shared__ int cnt[64], excL[64], rnk[64];
    __shared__ int lcsr[CAP / 2];
    const int t = threadIdx.x;
    const int bb = blockIdx.x >> 1;
    const int h = blockIdx.x & 1;
    const int tile0 = bb * 128;
    const int d0 = tile0 + h * 64;
    if (d0 >= N) return;
    const int beg = bb * CAP, end = bb * CAP + gcur[bb];
    const int excb = meta[d0].y;   // broadcast load (same addr all lanes)
    if (t < 64) {
        int d = d0 + t;
        int2 m = (d < N) ? meta[d] : make_int2(0, 0);
        cnt[t] = m.x;
        excL[t] = m.y - excb;      // invalid dsts: never referenced (cnt=0)
        rnk[t] = 0;
    }
    __syncthreads();
    for (int i = beg + t; i < end; i += 256) {
        int v = part[i];
        int dl = (v >> 17) & 127;
        if ((dl >> 6) == h) {
            int l = dl & 63;
            int r = atomicAdd(&rnk[l], 1);
            lcsr[excL[l] + r] = v & 0x1FFFF;
        }
    }
    __syncthreads();

    const int lane = t & 63;
    const int g = lane >> 4;        // group 0..3 within wave
    const int fl = lane & 15;       // feature quad
    const int wib = t >> 6;         // wave 0..3
    const int q = wib * 4 + g;      // group 0..15 in block
    const float slope = pa[0];
    const float4 b4 = ((const float4*)b)[fl];

    for (int dl = q; dl < 64; dl += 16) {
        int d = d0 + dl;
        if (d >= N) break;
        const int jb = excL[dl];
        const int n = cnt[dl];
        float ax = 0.f, ay = 0.f, az = 0.f, aw = 0.f;
        int j = 0;
        for (; j + 7 < n; j += 8) {
            int s0 = lcsr[jb + j],     s1 = lcsr[jb + j + 1];
            int s2 = lcsr[jb + j + 2], s3 = lcsr[jb + j + 3];
            int s4 = lcsr[jb + j + 4], s5 = lcsr[jb + j + 5];
            int s6 = lcsr[jb + j + 6], s7 = lcsr[jb + j + 7];
            uint2 u0 = *(const uint2*)(xwsh + (long long)s0 * 64 + 4 * fl);
            uint2 u1 = *(const uint2*)(xwsh + (long long)s1 * 64 + 4 * fl);
            uint2 u2 = *(const uint2*)(xwsh + (long long)s2 * 64 + 4 * fl);
            uint2 u3 = *(const uint2*)(xwsh + (long long)s3 * 64 + 4 * fl);
            uint2 u4 = *(const uint2*)(xwsh + (long long)s4 * 64 + 4 * fl);
            uint2 u5 = *(const uint2*)(xwsh + (long long)s5 * 64 + 4 * fl);
            uint2 u6 = *(const uint2*)(xwsh + (long long)s6 * 64 + 4 * fl);
            uint2 u7 = *(const uint2*)(xwsh + (long long)s7 * 64 + 4 * fl);
            float2 f0a = __half22float2(*(const __half2*)&u0.x);
            float2 f0b = __half22float2(*(const __half2*)&u0.y);
            float2 f1a = __half22float2(*(const __half2*)&u1.x);
            float2 f1b = __half22float2(*(const __half2*)&u1.y);
            float2 f2a = __half22float2(*(const __half2*)&u2.x);
            float2 f2b = __half22float2(*(const __half2*)&u2.y);
            float2 f3a = __half22float2(*(const __half2*)&u3.x);
            float2 f3b = __half22float2(*(const __half2*)&u3.y);
            float2 f4a = __half22float2(*(const __half2*)&u4.x);
            float2 f4b = __half22float2(*(const __half2*)&u4.y);
            float2 f5a = __half22float2(*(const __half2*)&u5.x);
            float2 f5b = __half22float2(*(const __half2*)&u5.y);
            float2 f6a = __half22float2(*(const __half2*)&u6.x);
            float2 f6b = __half22float2(*(const __half2*)&u6.y);
            float2 f7a = __half22float2(*(const __half2*)&u7.x);
            float2 f7b = __half22float2(*(const __half2*)&u7.y);
            ax += ((f0a.x + f1a.x) + (f2a.x + f3a.x)) +
                  ((f4a.x + f5a.x) + (f6a.x + f7a.x));
            ay += ((f0a.y + f1a.y) + (f2a.y + f3a.y)) +
                  ((f4a.y + f5a.y) + (f6a.y + f7a.y));
            az += ((f0b.x + f1b.x) + (f2b.x + f3b.x)) +
                  ((f4b.x + f5b.x) + (f6b.x + f7b.x));
            aw += ((f0b.y + f1b.y) + (f2b.y + f3b.y)) +
                  ((f4b.y + f5b.y) + (f6b.y + f7b.y));
        }
        for (; j + 3 < n; j += 4) {
            int s0 = lcsr[jb + j],     s1 = lcsr[jb + j + 1];
            int s2 = lcsr[jb + j + 2], s3 = lcsr[jb + j + 3];
            uint2 u0 = *(const uint2*)(xwsh + (long long)s0 * 64 + 4 * fl);
            uint2 u1 = *(const uint2*)(xwsh + (long long)s1 * 64 + 4 * fl);
            uint2 u2 = *(const uint2*)(xwsh + (long long)s2 * 64 + 4 * fl);
            uint2 u3 = *(const uint2*)(xwsh + (long long)s3 * 64 + 4 * fl);
            float2 f0a = __half22float2(*(const __half2*)&u0.x);
            float2 f0b = __half22float2(*(const __half2*)&u0.y);
            float2 f1a = __half22float2(*(const __half2*)&u1.x);
            float2 f1b = __half22float2(*(const __half2*)&u1.y);
            float2 f2a = __half22float2(*(const __half2*)&u2.x);
            float2 f2b = __half22float2(*(const __half2*)&u2.y);
            float2 f3a = __half22float2(*(const __half2*)&u3.x);
            float2 f3b = __half22float2(*(const __half2*)&u3.y);
            ax += (f0a.x + f1a.x) + (f2a.x + f3a.x);
            ay += (f0a.y + f1a.y) + (f2a.y + f3a.y);
            az += (f0b.x + f1b.x) + (f2b.x + f3b.x);
            aw += (f0b.y + f1b.y) + (f2b.y + f3b.y);
        }
        for (; j < n; ++j) {
            int s = lcsr[jb + j];
            uint2 u = *(const uint2*)(xwsh + (long long)s * 64 + 4 * fl);
            float2 f01 = __half22float2(*(const __half2*)&u.x);
            float2 f23 = __half22float2(*(const __half2*)&u.y);
            ax += f01.x; ay += f01.y; az += f23.x; aw += f23.y;
        }
        uint2 u = *(const uint2*)(xwsh + (long long)d * 64 + 4 * fl);  // self
        float2 s01 = __half22float2(*(const __half2*)&u.x);
        float2 s23 = __half22float2(*(const __half2*)&u.y);
        float di = rsqrtf((float)n + 1.0f);
        float4 v;
        v.x = di * (ax + s01.x) + b4.x;
        v.y = di * (ay + s01.y) + b4.y;
        v.z = di * (az + s23.x) + b4.z;
        v.w = di * (aw + s23.y) + b4.w;
        v.x = v.x >= 0.f ? v.x : slope * v.x;
        v.y = v.y >= 0.f ? v.y : slope * v.y;
        v.z = v.z >= 0.f ? v.z : slope * v.z;
        v.w = v.w >= 0.f ? v.w : slope * v.w;
        *(float4*)(out + (long long)d * 64 + 4 * fl) = v;
    }
}

extern "C" void kernel_launch(void* const* d_in, const int* in_sizes, int n_in,
                              void* d_out, int out_size, void* d_ws, size_t ws_size,
                              hipStream_t stream) {
    const float* x  = (const float*)d_in[0];
    const int*   ei = (const int*)d_in[1];
    const float* W  = (const float*)d_in[2];
    const float* b  = (const float*)d_in[3];
    const float* pa = (const float*)d_in[4];
    float* out = (float*)d_out;

    const int N = in_sizes[0] / 64;
    const long long E = (long long)in_sizes[1] / 2;
    const int nbuk = (N + 127) >> 7;           // 782 for N=100k (<= NBUK_MAX)
    int nscat = iceil(E, SCTH * BUFK);
    if (nscat < 256) nscat = 256;              // keep all CUs busy
    const int chunk = iceil(E, nscat);

    char* ws = (char*)d_ws;
    size_t o = 0;
    int*    gcur  = (int*)(ws + o);   o += ((size_t)nbuk * 4 + 255) & ~(size_t)255;
    int2*   meta  = (int2*)(ws + o);  o += ((size_t)N * 8 + 255) & ~(size_t)255;
    int*    part  = (int*)(ws + o);   o += ((size_t)nbuk * CAP * 4 + 255) & ~(size_t)255;
    __half* xwsh  = (__half*)(ws + o);  // N*64*2 = 12.8 MB; total ~27 MB

    hipMemsetAsync(gcur, 0, (size_t)nbuk * 4, stream);
    k_scat<<<nscat, SCTH, 0, stream>>>(ei, gcur, part, E, nbuk, chunk,
                                       (long long)in_sizes[1]);
    k_gemmmeta<<<nbuk, 256, 0, stream>>>(part, gcur, x, W, meta, xwsh, N);
    k_gfuse<<<nbuk * 2, 256, 0, stream>>>(part, gcur, meta, xwsh, b, pa, out, N);
}